// Round 12
// baseline (254.047 us; speedup 1.0000x reference)
//
#include <hip/hip_runtime.h>
#include <hip/hip_bf16.h>

#define N_NODES 100000
#define EMB     64
#define N_EDGES 1200000
#define ALPHA   0.25f
#define SCAN_CHUNK 1024
#define NPART ((N_NODES + SCAN_CHUNK - 1) / SCAN_CHUNK)   // 98

// ---------------------------------------------------------------------------
// Format detection — multi-block sampled. Evidence-only flags, OR-accumulated:
//   flags[0] != 0  ->  mask has nonzero bytes at i%4!=0  ->  1-byte bool
//   flags[1] != 0  ->  idx has nonzero odd words         ->  int32 (NOT i64)
// ---------------------------------------------------------------------------
__global__ void k_detect(const unsigned char* maskB, const int* idx, int* flags) {
    int tid = blockIdx.x * blockDim.x + threadIdx.x;    // 64 x 256 = 16384
    int lane = threadIdx.x & 63;
    bool mev = (tid & 3) && maskB[tid];
    if (__any(mev) && lane == 0) atomicOr(&flags[0], 1);
    bool iev = (tid < 4096) && (idx[2 * tid + 1] != 0);
    if (__any(iev) && lane == 0) atomicOr(&flags[1], 1);
}

__device__ __forceinline__ int idx_row(const int* idx, int i64, int e) {
    return i64 ? idx[2 * e] : idx[e];
}
__device__ __forceinline__ int idx_col(const int* idx, int i64, int e) {
    return i64 ? idx[2 * (N_EDGES + e)] : idx[N_EDGES + e];
}
__device__ __forceinline__ int edge_mask(const void* maskp, int mbool, int e) {
    return mbool ? (int)((const unsigned char*)maskp)[e] : ((const int*)maskp)[e];
}

// ONE int atomic per active edge; return value = edge's rank within its node.
__global__ void k_hist(const float* __restrict__ ea, const void* maskp,
                       const int* __restrict__ idx, const int* __restrict__ flags,
                       int* __restrict__ cnt, int* __restrict__ rank) {
    int e = blockIdx.x * blockDim.x + threadIdx.x;
    if (e >= N_EDGES) return;
    int mbool = flags[0] != 0, i64 = (flags[1] == 0);
    if (!edge_mask(maskp, mbool, e)) return;
    float wv = ea[e];
    if (wv == 0.0f) return;
    int c = idx_col(idx, i64, e);
    if ((unsigned)c >= N_NODES) return;
    rank[e] = atomicAdd(&cnt[c], 1);
}

// Single-kernel scan: slices need only be disjoint, not globally ordered.
// Block local-scans 1024 counts, claims base via one atomicAdd on gTotal.
__global__ void k_scanx(const int* __restrict__ cnt, int* __restrict__ gTotal,
                        int* __restrict__ row_start) {
    __shared__ int sh[256];
    __shared__ int sbase;
    int tid = threadIdx.x;
    int base = blockIdx.x * SCAN_CHUNK + tid * 4;
    int v[4];
    int s = 0;
#pragma unroll
    for (int k = 0; k < 4; ++k) {
        int i = base + k;
        v[k] = (i < N_NODES) ? cnt[i] : 0;
        s += v[k];
    }
    sh[tid] = s;
    __syncthreads();
    for (int d = 1; d < 256; d <<= 1) {
        int t = (tid >= d) ? sh[tid - d] : 0;
        __syncthreads();
        sh[tid] += t;
        __syncthreads();
    }
    if (tid == 255) sbase = atomicAdd(gTotal, sh[255]);
    __syncthreads();
    int off = sbase + sh[tid] - s;                 // exclusive within block
#pragma unroll
    for (int k = 0; k < 4; ++k) {
        int i = base + k;
        if (i < N_NODES) { row_start[i] = off; off += v[k]; }
    }
}

// Fill CSR — atomic-free: slot p = row_start[col] + rank[e]. Entry stores
// RAW weight + src row; normalization is applied on the fly in the gathers
// (R12: k_normfix deleted — csr is read-only after this point).
__global__ void k_fill(const float* __restrict__ ea, const void* maskp,
                       const int* __restrict__ idx, const int* __restrict__ flags,
                       const int* __restrict__ row_start, const int* __restrict__ rank,
                       int2* __restrict__ csr) {
    int e = blockIdx.x * blockDim.x + threadIdx.x;
    if (e >= N_EDGES) return;
    int mbool = flags[0] != 0, i64 = (flags[1] == 0);
    if (!edge_mask(maskp, mbool, e)) return;
    float wv = ea[e];
    if (wv == 0.0f) return;
    int c = idx_col(idx, i64, e);
    if ((unsigned)c >= N_NODES) return;
    int r = idx_row(idx, i64, e);
    int rok = (unsigned)r < N_NODES;
    int p = row_start[c] + rank[e];
    if ((unsigned)p < N_EDGES)
        csr[p] = make_int2(__float_as_int(rok ? wv : 0.0f), rok ? r : 0);
}

__device__ __forceinline__ void slice_bounds(const int* row_start, const int* cnt,
                                             int n, int& beg, int& end) {
    beg = row_start[n];
    if (beg < 0) beg = 0;
    if (beg > N_EDGES) beg = N_EDGES;
    int c = cnt[n];
    if (c < 0) c = 0;
    end = beg + c;
    if (end > N_EDGES) end = N_EDGES;
}

// Weighted degree from CSR slices (streaming, no atomics) -> dinv.
__global__ void k_deg(const int* __restrict__ row_start, const int* __restrict__ cnt,
                      const int2* __restrict__ csr, float* __restrict__ dinv) {
    int n = blockIdx.x * blockDim.x + threadIdx.x;
    if (n >= N_NODES) return;
    int beg, end;
    slice_bounds(row_start, cnt, n, beg, end);
    float s = 0.0f;
    for (int p = beg; p < end; ++p) s += __int_as_float(csr[p].x);
    dinv[n] = (s > 0.0f) ? rsqrtf(s) : 0.0f;
}

// Aggregation core: 16 lanes per node, float4 per lane (4 nodes/wave).
// R12: batch-8 (double the outstanding row-fetches per wave — gathers are
// bound by random-row service rate, and post-R10 each edge is only 16
// requests so concurrency is the lever) + on-the-fly norm: per edge load
// dinv[r] (L2-hot 400 KB, broadcast, independent of the row fetch), weight
// = w * dinv[r]; final sum scaled by dinv[n]. Masked slots redirect to
// L1-hot entries with w=0.
__device__ __forceinline__ float4 gather_core(
        const int* __restrict__ row_start, const int* __restrict__ cnt,
        const int2* __restrict__ csr, const float* __restrict__ dinv,
        const float4* __restrict__ h4, int n, int q) {
    int beg, end;
    slice_bounds(row_start, cnt, n, beg, end);
    float dn = dinv[n];
    float4 s = make_float4(0.f, 0.f, 0.f, 0.f);
    for (int j = beg; j < end; j += 8) {
        int last = end - 1;
        float ww[8];
        int   rr[8];
#pragma unroll
        for (int k = 0; k < 8; ++k) {
            int  jk = j + k;
            bool a  = jk < end;
            int2 p  = csr[a ? jk : last];
            int  r  = a ? min((unsigned)p.y, (unsigned)(N_NODES - 1)) : 0;
            rr[k] = r;
            ww[k] = a ? __int_as_float(p.x) * dinv[r] : 0.0f;
        }
#pragma unroll
        for (int k = 0; k < 8; ++k) {
            float4 v = h4[(size_t)rr[k] * 16 + q];
            s.x += ww[k] * v.x; s.y += ww[k] * v.y;
            s.z += ww[k] * v.z; s.w += ww[k] * v.w;
        }
    }
    s.x *= dn; s.y *= dn; s.z *= dn; s.w *= dn;
    return s;
}

// Mid layer: h_next = A_hat @ h. No acc traffic.
__global__ __launch_bounds__(256) void k_gather_mid(
        const int* __restrict__ row_start, const int* __restrict__ cnt,
        const int2* __restrict__ csr, const float* __restrict__ dinv,
        const float* __restrict__ hsrc, float* __restrict__ hdst) {
    int t = blockIdx.x * blockDim.x + threadIdx.x;
    int n = t >> 4;
    int q = t & 15;
    if (n >= N_NODES) return;
    float4 s = gather_core(row_start, cnt, csr, dinv, (const float4*)hsrc, n, q);
    ((float4*)hdst)[(size_t)n * 16 + q] = s;
}

// Last layer: s = A_hat @ h2, then out = ALPHA*(x + h1 + h2 + s) directly.
__global__ __launch_bounds__(256) void k_gather_last(
        const int* __restrict__ row_start, const int* __restrict__ cnt,
        const int2* __restrict__ csr, const float* __restrict__ dinv,
        const float* __restrict__ x, const float* __restrict__ h1,
        const float* __restrict__ h2, float* __restrict__ out) {
    int t = blockIdx.x * blockDim.x + threadIdx.x;
    int n = t >> 4;
    int q = t & 15;
    if (n >= N_NODES) return;
    float4 s = gather_core(row_start, cnt, csr, dinv, (const float4*)h2, n, q);
    size_t o = (size_t)n * 16 + q;
    float4 xv = ((const float4*)x)[o];
    float4 a1 = ((const float4*)h1)[o];
    float4 a2 = ((const float4*)h2)[o];
    ((float4*)out)[o] = make_float4(
        ALPHA * (xv.x + a1.x + a2.x + s.x),
        ALPHA * (xv.y + a1.y + a2.y + s.y),
        ALPHA * (xv.z + a1.z + a2.z + s.z),
        ALPHA * (xv.w + a1.w + a2.w + s.w));
}

extern "C" void kernel_launch(void* const* d_in, const int* in_sizes, int n_in,
                              void* d_out, int out_size, void* d_ws, size_t ws_size,
                              hipStream_t stream) {
    const float* x   = (const float*)d_in[0];
    const float* ea  = (const float*)d_in[1];
    const int*   idx = (const int*)d_in[2];
    const void*  msk = d_in[3];
    float*       out = (float*)d_out;

    char* ws = (char*)d_ws;
    size_t off = 0;
    auto alloc = [&](size_t bytes) -> void* {
        void* p = ws + off;
        off = (off + bytes + 255) & ~(size_t)255;
        return p;
    };
    int*   flags     = (int*)  alloc(64);   // flags[0..1] + gTotal at flags[8]
    int*   cnt       = (int*)  alloc(sizeof(int)   * N_NODES);
    int*   row_start = (int*)  alloc(sizeof(int)   * N_NODES);
    float* dinv      = (float*)alloc(sizeof(float) * N_NODES);
    int*   rank      = (int*)  alloc(sizeof(int)   * N_EDGES);
    int2*  csr       = (int2*) alloc(sizeof(int2)  * N_EDGES);
    float* hA        = (float*)alloc(sizeof(float) * (size_t)N_NODES * EMB);
    float* hB        = (float*)alloc(sizeof(float) * (size_t)N_NODES * EMB);
    int*   gTotal    = flags + 8;

    const int B = 256;
    const int gE = (N_EDGES + B - 1) / B;
    const int gN = (N_NODES + B - 1) / B;
    const int gG = (N_NODES * 16 + B - 1) / B;   // 6250 blocks, 16 lanes/node

    // flags block + cnt are adjacent in ws -> one memset zeroes both.
    hipMemsetAsync(flags, 0, (size_t)((char*)row_start - (char*)flags), stream);
    k_detect <<<64, 256, 0, stream>>>((const unsigned char*)msk, idx, flags);
    k_hist   <<<gE, B, 0, stream>>>(ea, msk, idx, flags, cnt, rank);
    k_scanx  <<<NPART, 256, 0, stream>>>(cnt, gTotal, row_start);
    k_fill   <<<gE, B, 0, stream>>>(ea, msk, idx, flags, row_start, rank, csr);
    k_deg    <<<gN, B, 0, stream>>>(row_start, cnt, csr, dinv);

    k_gather_mid <<<gG, B, 0, stream>>>(row_start, cnt, csr, dinv, x,  hA);
    k_gather_mid <<<gG, B, 0, stream>>>(row_start, cnt, csr, dinv, hA, hB);
    k_gather_last<<<gG, B, 0, stream>>>(row_start, cnt, csr, dinv, x, hA, hB, out);
}

// Round 13
// 231.639 us; speedup vs baseline: 1.0967x; 1.0967x over previous
//
#include <hip/hip_runtime.h>
#include <hip/hip_bf16.h>

#define N_NODES 100000
#define EMB     64
#define N_EDGES 1200000
#define ALPHA   0.25f
#define SCAN_CHUNK 1024
#define NPART ((N_NODES + SCAN_CHUNK - 1) / SCAN_CHUNK)   // 98

// ---------------------------------------------------------------------------
// Format detection — multi-block sampled. Evidence-only flags, OR-accumulated:
//   flags[0] != 0  ->  mask has nonzero bytes at i%4!=0  ->  1-byte bool
//   flags[1] != 0  ->  idx has nonzero odd words         ->  int32 (NOT i64)
// ---------------------------------------------------------------------------
__global__ void k_detect(const unsigned char* maskB, const int* idx, int* flags) {
    int tid = blockIdx.x * blockDim.x + threadIdx.x;    // 64 x 256 = 16384
    int lane = threadIdx.x & 63;
    bool mev = (tid & 3) && maskB[tid];
    if (__any(mev) && lane == 0) atomicOr(&flags[0], 1);
    bool iev = (tid < 4096) && (idx[2 * tid + 1] != 0);
    if (__any(iev) && lane == 0) atomicOr(&flags[1], 1);
}

__device__ __forceinline__ int idx_row(const int* idx, int i64, int e) {
    return i64 ? idx[2 * e] : idx[e];
}
__device__ __forceinline__ int idx_col(const int* idx, int i64, int e) {
    return i64 ? idx[2 * (N_EDGES + e)] : idx[N_EDGES + e];
}
__device__ __forceinline__ int edge_mask(const void* maskp, int mbool, int e) {
    return mbool ? (int)((const unsigned char*)maskp)[e] : ((const int*)maskp)[e];
}

// ONE int atomic per active edge; return value = edge's rank within its node.
__global__ void k_hist(const float* __restrict__ ea, const void* maskp,
                       const int* __restrict__ idx, const int* __restrict__ flags,
                       int* __restrict__ cnt, int* __restrict__ rank) {
    int e = blockIdx.x * blockDim.x + threadIdx.x;
    if (e >= N_EDGES) return;
    int mbool = flags[0] != 0, i64 = (flags[1] == 0);
    if (!edge_mask(maskp, mbool, e)) return;
    float wv = ea[e];
    if (wv == 0.0f) return;
    int c = idx_col(idx, i64, e);
    if ((unsigned)c >= N_NODES) return;
    rank[e] = atomicAdd(&cnt[c], 1);
}

// Single-kernel scan: slices need only be disjoint, not globally ordered.
// Block local-scans 1024 counts, claims base via one atomicAdd on gTotal.
__global__ void k_scanx(const int* __restrict__ cnt, int* __restrict__ gTotal,
                        int* __restrict__ row_start) {
    __shared__ int sh[256];
    __shared__ int sbase;
    int tid = threadIdx.x;
    int base = blockIdx.x * SCAN_CHUNK + tid * 4;
    int v[4];
    int s = 0;
#pragma unroll
    for (int k = 0; k < 4; ++k) {
        int i = base + k;
        v[k] = (i < N_NODES) ? cnt[i] : 0;
        s += v[k];
    }
    sh[tid] = s;
    __syncthreads();
    for (int d = 1; d < 256; d <<= 1) {
        int t = (tid >= d) ? sh[tid - d] : 0;
        __syncthreads();
        sh[tid] += t;
        __syncthreads();
    }
    if (tid == 255) sbase = atomicAdd(gTotal, sh[255]);
    __syncthreads();
    int off = sbase + sh[tid] - s;                 // exclusive within block
#pragma unroll
    for (int k = 0; k < 4; ++k) {
        int i = base + k;
        if (i < N_NODES) { row_start[i] = off; off += v[k]; }
    }
}

// Fill CSR — atomic-free: slot p = row_start[col] + rank[e]. Entry stores
// RAW weight + src row; normalization applied on the fly in the gathers.
__global__ void k_fill(const float* __restrict__ ea, const void* maskp,
                       const int* __restrict__ idx, const int* __restrict__ flags,
                       const int* __restrict__ row_start, const int* __restrict__ rank,
                       int2* __restrict__ csr) {
    int e = blockIdx.x * blockDim.x + threadIdx.x;
    if (e >= N_EDGES) return;
    int mbool = flags[0] != 0, i64 = (flags[1] == 0);
    if (!edge_mask(maskp, mbool, e)) return;
    float wv = ea[e];
    if (wv == 0.0f) return;
    int c = idx_col(idx, i64, e);
    if ((unsigned)c >= N_NODES) return;
    int r = idx_row(idx, i64, e);
    int rok = (unsigned)r < N_NODES;
    int p = row_start[c] + rank[e];
    if ((unsigned)p < N_EDGES)
        csr[p] = make_int2(__float_as_int(rok ? wv : 0.0f), rok ? r : 0);
}

__device__ __forceinline__ void slice_bounds(const int* row_start, const int* cnt,
                                             int n, int& beg, int& end) {
    beg = row_start[n];
    if (beg < 0) beg = 0;
    if (beg > N_EDGES) beg = N_EDGES;
    int c = cnt[n];
    if (c < 0) c = 0;
    end = beg + c;
    if (end > N_EDGES) end = N_EDGES;
}

// Weighted degree from CSR slices (streaming, no atomics) -> dinv.
__global__ void k_deg(const int* __restrict__ row_start, const int* __restrict__ cnt,
                      const int2* __restrict__ csr, float* __restrict__ dinv) {
    int n = blockIdx.x * blockDim.x + threadIdx.x;
    if (n >= N_NODES) return;
    int beg, end;
    slice_bounds(row_start, cnt, n, beg, end);
    float s = 0.0f;
    for (int p = beg; p < end; ++p) s += __int_as_float(csr[p].x);
    dinv[n] = (s > 0.0f) ? rsqrtf(s) : 0.0f;
}

// Aggregation core: 16 lanes per node, float4 per lane (4 nodes/wave).
// R13: back to batch-4 (R12 post-mortem: batch-8's VGPR 20->36 cut occupancy
// 68->52% — in a latency-bound kernel resident waves are the cheap
// concurrency; ILP past x4 costs more than it adds). On-the-fly norm kept
// (single variable vs R11): weight = w * dinv[r] (4 B L2-hot broadcast,
// independent of the row fetch), final sum scaled by dinv[n] — deletes the
// k_normfix pass. Masked slots redirect to L1-hot entries with w=0.
__device__ __forceinline__ float4 gather_core(
        const int* __restrict__ row_start, const int* __restrict__ cnt,
        const int2* __restrict__ csr, const float* __restrict__ dinv,
        const float4* __restrict__ h4, int n, int q) {
    int beg, end;
    slice_bounds(row_start, cnt, n, beg, end);
    float dn = dinv[n];
    float4 s = make_float4(0.f, 0.f, 0.f, 0.f);
    for (int j = beg; j < end; j += 4) {
        int last = end - 1;
        int j1 = j + 1 < last ? j + 1 : last;
        int j2 = j + 2 < last ? j + 2 : last;
        int j3 = j + 3 < last ? j + 3 : last;
        int2 p0 = csr[j];
        int2 p1 = csr[j1];
        int2 p2 = csr[j2];
        int2 p3 = csr[j3];
        bool a1 = j + 1 < end, a2 = j + 2 < end, a3 = j + 3 < end;
        int r0 = min((unsigned)p0.y, (unsigned)(N_NODES - 1));
        int r1 = a1 ? min((unsigned)p1.y, (unsigned)(N_NODES - 1)) : 0;
        int r2 = a2 ? min((unsigned)p2.y, (unsigned)(N_NODES - 1)) : 0;
        int r3 = a3 ? min((unsigned)p3.y, (unsigned)(N_NODES - 1)) : 0;
        float w0 = __int_as_float(p0.x) * dinv[r0];
        float w1 = a1 ? __int_as_float(p1.x) * dinv[r1] : 0.0f;
        float w2 = a2 ? __int_as_float(p2.x) * dinv[r2] : 0.0f;
        float w3 = a3 ? __int_as_float(p3.x) * dinv[r3] : 0.0f;
        float4 v0 = h4[(size_t)r0 * 16 + q];
        float4 v1 = h4[(size_t)r1 * 16 + q];
        float4 v2 = h4[(size_t)r2 * 16 + q];
        float4 v3 = h4[(size_t)r3 * 16 + q];
        s.x += w0 * v0.x; s.y += w0 * v0.y; s.z += w0 * v0.z; s.w += w0 * v0.w;
        s.x += w1 * v1.x; s.y += w1 * v1.y; s.z += w1 * v1.z; s.w += w1 * v1.w;
        s.x += w2 * v2.x; s.y += w2 * v2.y; s.z += w2 * v2.z; s.w += w2 * v2.w;
        s.x += w3 * v3.x; s.y += w3 * v3.y; s.z += w3 * v3.z; s.w += w3 * v3.w;
    }
    s.x *= dn; s.y *= dn; s.z *= dn; s.w *= dn;
    return s;
}

// Mid layer: h_next = A_hat @ h. No acc traffic.
__global__ __launch_bounds__(256) void k_gather_mid(
        const int* __restrict__ row_start, const int* __restrict__ cnt,
        const int2* __restrict__ csr, const float* __restrict__ dinv,
        const float* __restrict__ hsrc, float* __restrict__ hdst) {
    int t = blockIdx.x * blockDim.x + threadIdx.x;
    int n = t >> 4;
    int q = t & 15;
    if (n >= N_NODES) return;
    float4 s = gather_core(row_start, cnt, csr, dinv, (const float4*)hsrc, n, q);
    ((float4*)hdst)[(size_t)n * 16 + q] = s;
}

// Last layer: s = A_hat @ h2, then out = ALPHA*(x + h1 + h2 + s) directly.
__global__ __launch_bounds__(256) void k_gather_last(
        const int* __restrict__ row_start, const int* __restrict__ cnt,
        const int2* __restrict__ csr, const float* __restrict__ dinv,
        const float* __restrict__ x, const float* __restrict__ h1,
        const float* __restrict__ h2, float* __restrict__ out) {
    int t = blockIdx.x * blockDim.x + threadIdx.x;
    int n = t >> 4;
    int q = t & 15;
    if (n >= N_NODES) return;
    float4 s = gather_core(row_start, cnt, csr, dinv, (const float4*)h2, n, q);
    size_t o = (size_t)n * 16 + q;
    float4 xv = ((const float4*)x)[o];
    float4 a1 = ((const float4*)h1)[o];
    float4 a2 = ((const float4*)h2)[o];
    ((float4*)out)[o] = make_float4(
        ALPHA * (xv.x + a1.x + a2.x + s.x),
        ALPHA * (xv.y + a1.y + a2.y + s.y),
        ALPHA * (xv.z + a1.z + a2.z + s.z),
        ALPHA * (xv.w + a1.w + a2.w + s.w));
}

extern "C" void kernel_launch(void* const* d_in, const int* in_sizes, int n_in,
                              void* d_out, int out_size, void* d_ws, size_t ws_size,
                              hipStream_t stream) {
    const float* x   = (const float*)d_in[0];
    const float* ea  = (const float*)d_in[1];
    const int*   idx = (const int*)d_in[2];
    const void*  msk = d_in[3];
    float*       out = (float*)d_out;

    char* ws = (char*)d_ws;
    size_t off = 0;
    auto alloc = [&](size_t bytes) -> void* {
        void* p = ws + off;
        off = (off + bytes + 255) & ~(size_t)255;
        return p;
    };
    int*   flags     = (int*)  alloc(64);   // flags[0..1] + gTotal at flags[8]
    int*   cnt       = (int*)  alloc(sizeof(int)   * N_NODES);
    int*   row_start = (int*)  alloc(sizeof(int)   * N_NODES);
    float* dinv      = (float*)alloc(sizeof(float) * N_NODES);
    int*   rank      = (int*)  alloc(sizeof(int)   * N_EDGES);
    int2*  csr       = (int2*) alloc(sizeof(int2)  * N_EDGES);
    float* hA        = (float*)alloc(sizeof(float) * (size_t)N_NODES * EMB);
    float* hB        = (float*)alloc(sizeof(float) * (size_t)N_NODES * EMB);
    int*   gTotal    = flags + 8;

    const int B = 256;
    const int gE = (N_EDGES + B - 1) / B;
    const int gN = (N_NODES + B - 1) / B;
    const int gG = (N_NODES * 16 + B - 1) / B;   // 6250 blocks, 16 lanes/node

    // flags block + cnt are adjacent in ws -> one memset zeroes both.
    hipMemsetAsync(flags, 0, (size_t)((char*)row_start - (char*)flags), stream);
    k_detect <<<64, 256, 0, stream>>>((const unsigned char*)msk, idx, flags);
    k_hist   <<<gE, B, 0, stream>>>(ea, msk, idx, flags, cnt, rank);
    k_scanx  <<<NPART, 256, 0, stream>>>(cnt, gTotal, row_start);
    k_fill   <<<gE, B, 0, stream>>>(ea, msk, idx, flags, row_start, rank, csr);
    k_deg    <<<gN, B, 0, stream>>>(row_start, cnt, csr, dinv);

    k_gather_mid <<<gG, B, 0, stream>>>(row_start, cnt, csr, dinv, x,  hA);
    k_gather_mid <<<gG, B, 0, stream>>>(row_start, cnt, csr, dinv, hA, hB);
    k_gather_last<<<gG, B, 0, stream>>>(row_start, cnt, csr, dinv, x, hA, hB, out);
}